// Round 14
// baseline (796.823 us; speedup 1.0000x reference)
//
#include <hip/hip_runtime.h>
#include <hip/hip_fp16.h>

// LinearCDE chunked parallel scan, MFMA edition, adaptive workspace.
//   y_t = y_{t-1} + A_t y_{t-1} + b_t;  A_t = reshape(inp_t @ Wa^T, [H,H])
// R14: SC cap 64 -> 32. R12 evidence: pair FETCH=68MB on a 134MB A slice
// read immediately after amat wrote it — only ~half the A reads hit the
// 256MB Infinity Cache at SC=64 (slice A=134MB + Mr/Sr/Bs/out thrashes).
// At SC=32 the A slice is a fixed 67MB buffer reused 8x: amat writes
// allocate in LLC, chunkmap+emit reads hit LLC, and next slice's amat
// overwrites the same lines in place (dirty data never written back).
// Chunk math is SC-independent -> bit-identical results (absmax 0.25).
// Pipeline otherwise = R13: amat v2, chunkmap (7 serial fused compositions),
// comp4 (chunk->supermaps), chainsuper, fill, emit.

typedef _Float16 h8 __attribute__((ext_vector_type(8)));
typedef float v4f __attribute__((ext_vector_type(4)));
typedef unsigned int uint;

constexpr int B_ = 8, S_ = 2048, D_ = 64, H_ = 128;
constexpr int T_ = S_ - 1;              // 2047
constexpr int KD = D_ + 1;              // 65
constexpr float DTC = 1.0f / 2047.0f;
constexpr int L_ = 8;                   // chunk length
constexpr int LSH = 3;                  // log2(L_)
constexpr int NC = 256;                 // chunks per batch (last has 7 steps)

// ---------------- prep ----------------
__global__ __launch_bounds__(256) void k_prep_wa(const float* __restrict__ Wa,
                                                 _Float16* __restrict__ Wa16B,
                                                 float* __restrict__ Wa0) {
  int idx = blockIdx.x * 256 + threadIdx.x;     // 16384*64 exact
  int r = idx >> 6, kk = idx & 63;
  int rt = r >> 4, n = r & 15;
  int kb = kk >> 5, q = (kk >> 3) & 3, jj = kk & 7;
  float v = Wa[(size_t)r * KD + 1 + kk];
  Wa16B[((((size_t)rt * 2 + kb) * 4 + q) * 16 + n) * 8 + jj] = (_Float16)v;
  if (kk == 0) Wa0[r] = Wa[(size_t)r * KD];
}

__global__ __launch_bounds__(256) void k_prep_x(const float* __restrict__ X,
                                                _Float16* __restrict__ Xs16) {
  int idx = blockIdx.x * 256 + threadIdx.x;     // 16376*64 exact
  int bt = idx >> 6, d = idx & 63;
  int b = bt / T_, s = bt - b * T_;
  Xs16[(size_t)bt * 64 + d] = (_Float16)(X[((size_t)b * S_ + s + 1) * D_ + d] * DTC);
}

__global__ __launch_bounds__(128) void k_y0(const float* __restrict__ X,
                                            const float* __restrict__ Wi,
                                            const float* __restrict__ bi,
                                            float* __restrict__ out,
                                            float* __restrict__ ybound) {
  int b = blockIdx.x, h = threadIdx.x;
  __shared__ float xs[D_];
  if (h < D_) xs[h] = X[(size_t)b * S_ * D_ + h];
  __syncthreads();
  float acc = bi[h];
  const float* wr = Wi + h * D_;
#pragma unroll 8
  for (int d = 0; d < D_; d++) acc += xs[d] * wr[d];
  out[(size_t)b * S_ * H_ + h] = acc;
  if (ybound) ybound[(size_t)(b * NC + 0) * H_ + h] = acc;
}

__global__ __launch_bounds__(256) void k_bs(const float* __restrict__ X,
                                            const float* __restrict__ Wb,
                                            float* __restrict__ Bs) {
  __shared__ float wb_s[H_ * KD];
  __shared__ float xs[16][D_ + 4];
  int tid = threadIdx.x;
  int bt0 = blockIdx.x * 16;
  for (int i = tid; i < H_ * KD; i += 256) wb_s[i] = Wb[i];
  for (int i = tid; i < 16 * D_; i += 256) {
    int sl = i >> 6, d = i & 63;
    int btg = bt0 + sl;
    float v = 0.f;
    if (btg < B_ * T_) {
      int b = btg / T_, s = btg - b * T_;
      v = X[((size_t)b * S_ + s + 1) * D_ + d] * DTC;
    }
    xs[sl][d] = v;
  }
  __syncthreads();
  int h = tid & 127, sh = tid >> 7;
  const float* wrow = &wb_s[h * KD];
  for (int u = 0; u < 8; u++) {
    int sl = sh * 8 + u;
    int btg = bt0 + sl;
    if (btg >= B_ * T_) break;
    float acc = wrow[0] * DTC;
#pragma unroll 8
    for (int d = 0; d < D_; d++) acc += xs[sl][d] * wrow[1 + d];
    Bs[(size_t)btg * H_ + h] = acc;
  }
}

// ---------------- k_amat v2: 32t x 512el tiles, contiguous 1KB writes -----
__global__ __launch_bounds__(256) void k_amat(const _Float16* __restrict__ Xs16,
                                              const _Float16* __restrict__ Wa16B,
                                              const float* __restrict__ Wa0,
                                              _Float16* __restrict__ A_sl,
                                              int c0, int scShift) {
  __shared__ _Float16 sb[32 * 528];    // 33.8 KB
  int tid = threadIdx.x;
  int w = tid >> 6, lane = tid & 63;
  int n = lane & 15, q = lane >> 4;
  int rowbase = blockIdx.x * 32;
  int SCm = ((1 << scShift) << LSH) - 1;

  h8 af[2][2];
#pragma unroll
  for (int mi = 0; mi < 2; mi++) {
    int sidx = rowbase + mi * 16 + n;
    int b = sidx >> (scShift + LSH);
    int rem = sidx & SCm;
    int cc = rem >> LSH, l = rem & (L_ - 1);
    int s = (c0 + cc) * L_ + l;
    if (s >= T_) s = T_ - 1;
    size_t btg = (size_t)b * T_ + s;
#pragma unroll
    for (int kb = 0; kb < 2; kb++)
      af[mi][kb] = *(const h8*)(Xs16 + btg * 64 + kb * 32 + q * 8);
  }

  v4f acc[2][8];
#pragma unroll
  for (int nj = 0; nj < 8; nj++) {
    int ct_g = blockIdx.y * 32 + w * 8 + nj;
    float binit = DTC * Wa0[ct_g * 16 + n];
    h8 bf0 = *(const h8*)(Wa16B + ((((size_t)ct_g * 2 + 0) * 4 + q) * 16 + n) * 8);
    h8 bf1 = *(const h8*)(Wa16B + ((((size_t)ct_g * 2 + 1) * 4 + q) * 16 + n) * 8);
#pragma unroll
    for (int mi = 0; mi < 2; mi++) {
      v4f a;
      a[0] = binit; a[1] = binit; a[2] = binit; a[3] = binit;
      a = __builtin_amdgcn_mfma_f32_16x16x32_f16(af[mi][0], bf0, a, 0, 0, 0);
      a = __builtin_amdgcn_mfma_f32_16x16x32_f16(af[mi][1], bf1, a, 0, 0, 0);
      acc[mi][nj] = a;
    }
  }
#pragma unroll
  for (int mi = 0; mi < 2; mi++)
#pragma unroll
    for (int nj = 0; nj < 8; nj++)
#pragma unroll
      for (int reg = 0; reg < 4; reg++)
        sb[(mi * 16 + q * 4 + reg) * 528 + w * 128 + ((nj * 16 + n) ^ (q * 16))] =
            (_Float16)acc[mi][nj][reg];
  __syncthreads();
#pragma unroll
  for (int it = 0; it < 8; it++) {
    int idx = tid + it * 256;
    int t = idx >> 6, u4 = idx & 63;
    int qt = (t >> 2) & 3;
    uint4 val = *(const uint4*)&sb[t * 528 + ((u4 * 8) ^ (qt * 16))];
    *(uint4*)(A_sl + (size_t)(rowbase + t) * 16384 + blockIdx.y * 512 + u4 * 8) = val;
  }
}

// ---------------- k_chunkmap: chunk map via 7 serial compositions --------
__global__ __launch_bounds__(256) void k_chunkmap(const _Float16* __restrict__ A_sl,
                                                  const float* __restrict__ Bs,
                                                  _Float16* __restrict__ Mr,
                                                  float* __restrict__ vch,
                                                  int c0, int scShift) {
  __shared__ _Float16 Dt[128 * 136];
  __shared__ float v32[128];
  int tid = threadIdx.x;
  int w = tid >> 6, lane = tid & 63;
  int n = lane & 15, q = lane >> 4;
  int chunk = blockIdx.x;
  int SC = 1 << scShift;
  int b = chunk >> scShift;
  int cc = chunk & (SC - 1);
  int c = c0 + cc;
  int sbase = c * L_;
  int nsteps = min(L_, T_ - sbase);
  const _Float16* Abase = A_sl + (size_t)chunk * L_ * 16384;
  size_t btb = (size_t)b * T_ + sbase;

  // stage A0^T (conflict-free R10 mapping)
#pragma unroll
  for (int it = 0; it < 8; it++) {
    int idx = tid + it * 256;
    int rowl = idx & 127, c8 = (idx >> 7) * 8;
    uint4 pk = *(const uint4*)(Abase + rowl * 128 + c8);
    const _Float16* hp = (const _Float16*)&pk;
#pragma unroll
    for (int cx = 0; cx < 8; cx++) Dt[(c8 + cx) * 136 + rowl] = hp[cx];
  }
  if (tid < 128) v32[tid] = Bs[btb * 128 + tid];
  h8 idE, idO;
#pragma unroll
  for (int jj = 0; jj < 8; jj++) {
    idE[jj] = (_Float16)((q * 8 + jj == n) ? 1.f : 0.f);
    idO[jj] = (_Float16)((q * 8 + jj == 16 + n) ? 1.f : 0.f);
  }
  __syncthreads();

  v4f acc[2][8];
#pragma unroll
  for (int mi = 0; mi < 2; mi++) {
    int row0 = (2 * w + mi) * 16 + q * 4;
#pragma unroll
    for (int nj = 0; nj < 8; nj++) {
      int col = nj * 16 + n;
      union { uint2 u; _Float16 h[4]; } m2;
      m2.u = *(const uint2*)&Dt[col * 136 + row0];
#pragma unroll
      for (int reg = 0; reg < 4; reg++) acc[mi][nj][reg] = (float)m2.h[reg];
    }
  }

  int r0 = 2 * w * 16 + n, r1 = r0 + 16;
  h8 afA[2][4], afB[2][4];   // named double buffers, constant indices only

#define LOADA(dst, l)                                                                \
  {                                                                                  \
    const _Float16* Ag = Abase + (size_t)(l) * 16384;                                \
    _Pragma("unroll")                                                                \
    for (int mi = 0; mi < 2; mi++)                                                   \
      _Pragma("unroll")                                                              \
      for (int kb = 0; kb < 4; kb++)                                                 \
        dst[mi][kb] = *(const h8*)(Ag + ((2 * w + mi) * 16 + n) * 128 + kb * 32 + q * 8); \
  }

#define STEPQ(af, l)                                                                 \
  {                                                                                  \
    _Pragma("unroll")                                                                \
    for (int nj = 0; nj < 8; nj++) {                                                 \
      h8 bfr[4];                                                                     \
      _Pragma("unroll")                                                              \
      for (int kb = 0; kb < 4; kb++)                                                 \
        bfr[kb] = *(const h8*)&Dt[(nj * 16 + n) * 136 + kb * 32 + q * 8];            \
      _Pragma("unroll")                                                              \
      for (int mi = 0; mi < 2; mi++) {                                               \
        _Pragma("unroll")                                                            \
        for (int kb = 0; kb < 4; kb++)                                               \
          acc[mi][nj] = __builtin_amdgcn_mfma_f32_16x16x32_f16(af[mi][kb], bfr[kb], acc[mi][nj], 0, 0, 0); \
        acc[mi][nj] = __builtin_amdgcn_mfma_f32_16x16x32_f16(                        \
            af[mi][nj >> 1], (nj & 1) ? idO : idE, acc[mi][nj], 0, 0, 0);            \
      }                                                                              \
    }                                                                                \
    float dv0 = 0.f, dv1 = 0.f;                                                      \
    _Pragma("unroll")                                                                \
    for (int kb = 0; kb < 4; kb++) {                                                 \
      float4 p0 = *(const float4*)&v32[kb * 32 + q * 8];                             \
      float4 p1 = *(const float4*)&v32[kb * 32 + q * 8 + 4];                         \
      float vk[8] = {p0.x, p0.y, p0.z, p0.w, p1.x, p1.y, p1.z, p1.w};                \
      _Pragma("unroll")                                                              \
      for (int jj = 0; jj < 8; jj++) {                                               \
        dv0 += (float)af[0][kb][jj] * vk[jj];                                        \
        dv1 += (float)af[1][kb][jj] * vk[jj];                                        \
      }                                                                              \
    }                                                                                \
    dv0 += __shfl_xor(dv0, 16); dv0 += __shfl_xor(dv0, 32);                          \
    dv1 += __shfl_xor(dv1, 16); dv1 += __shfl_xor(dv1, 32);                          \
    float vold0 = v32[r0], vold1 = v32[r1];                                          \
    float bs0 = 0.f, bs1 = 0.f;                                                      \
    if (q == 0) {                                                                    \
      bs0 = Bs[(btb + (l)) * 128 + r0];                                              \
      bs1 = Bs[(btb + (l)) * 128 + r1];                                              \
    }                                                                                \
    __syncthreads();                                                                 \
    _Pragma("unroll")                                                                \
    for (int mi = 0; mi < 2; mi++) {                                                 \
      int row0 = (2 * w + mi) * 16 + q * 4;                                          \
      _Pragma("unroll")                                                              \
      for (int nj = 0; nj < 8; nj++) {                                               \
        int col = nj * 16 + n;                                                       \
        union { _Float16 h[4]; uint2 u; } pk;                                        \
        _Pragma("unroll")                                                            \
        for (int reg = 0; reg < 4; reg++) pk.h[reg] = (_Float16)acc[mi][nj][reg];    \
        *(uint2*)&Dt[col * 136 + row0] = pk.u;                                       \
      }                                                                              \
    }                                                                                \
    if (q == 0) {                                                                    \
      v32[r0] = vold0 + dv0 + bs0;                                                   \
      v32[r1] = vold1 + dv1 + bs1;                                                   \
    }                                                                                \
    __syncthreads();                                                                 \
  }

  LOADA(afA, 1);
  for (int l = 1; l < nsteps; l += 2) {
    if (l + 1 < nsteps) LOADA(afB, l + 1);
    STEPQ(afA, l);
    if (l + 2 < nsteps) LOADA(afA, l + 2);
    if (l + 1 < nsteps) STEPQ(afB, l + 1);
  }
#undef LOADA
#undef STEPQ

#pragma unroll
  for (int mi = 0; mi < 2; mi++) {
    int row0 = (2 * w + mi) * 16 + q * 4;
#pragma unroll
    for (int nj = 0; nj < 8; nj++) {
      int col = nj * 16 + n;
#pragma unroll
      for (int reg = 0; reg < 4; reg++)
        Dt[(row0 + reg) * 136 + col] = (_Float16)acc[mi][nj][reg];
    }
  }
  __syncthreads();
  _Float16* og = Mr + (size_t)chunk * 16384;
#pragma unroll
  for (int it = 0; it < 8; it++) {
    int idx = tid + it * 256;
    int rowl = idx >> 4, ch = idx & 15;
    uint4 val = *(const uint4*)&Dt[rowl * 136 + ch * 8];
    *(uint4*)(og + rowl * 128 + ch * 8) = val;
  }
  if (tid < 128) vch[(size_t)chunk * 128 + tid] = v32[tid];
}

// ---------------- k_comp4: compose 4 consecutive delta maps --------------
__global__ __launch_bounds__(256) void k_comp4(const _Float16* __restrict__ in_map,
                                               const float* __restrict__ in_v,
                                               _Float16* __restrict__ out_map,
                                               float* __restrict__ out_v) {
  __shared__ _Float16 Dt[128 * 136];    // D transposed
  __shared__ float v32[128];
  int tid = threadIdx.x;
  int w = tid >> 6, lane = tid & 63;
  int n = lane & 15, q = lane >> 4;
  size_t nbase = (size_t)blockIdx.x * 4;

  const _Float16* P0 = in_map + nbase * 16384;
#pragma unroll
  for (int it = 0; it < 8; it++) {
    int idx = tid + it * 256;
    int rowl = idx & 127, c8 = (idx >> 7) * 8;
    uint4 pk = *(const uint4*)(P0 + rowl * 128 + c8);
    const _Float16* hp = (const _Float16*)&pk;
#pragma unroll
    for (int cx = 0; cx < 8; cx++) Dt[(c8 + cx) * 136 + rowl] = hp[cx];
  }
  if (tid < 128) v32[tid] = in_v[nbase * 128 + tid];
  h8 idE, idO;
#pragma unroll
  for (int jj = 0; jj < 8; jj++) {
    idE[jj] = (_Float16)((q * 8 + jj == n) ? 1.f : 0.f);
    idO[jj] = (_Float16)((q * 8 + jj == 16 + n) ? 1.f : 0.f);
  }
  __syncthreads();

  v4f acc[2][8];
#pragma unroll
  for (int mi = 0; mi < 2; mi++) {
    int row0 = (2 * w + mi) * 16 + q * 4;
#pragma unroll
    for (int nj = 0; nj < 8; nj++) {
      int col = nj * 16 + n;
      union { uint2 u; _Float16 h[4]; } m2;
      m2.u = *(const uint2*)&Dt[col * 136 + row0];
#pragma unroll
      for (int reg = 0; reg < 4; reg++) acc[mi][nj][reg] = (float)m2.h[reg];
    }
  }

  int r0 = 2 * w * 16 + n, r1 = r0 + 16;
  for (int j = 1; j < 4; j++) {
    const _Float16* Pj = in_map + (nbase + j) * 16384;
    h8 af[2][4];
#pragma unroll
    for (int mi = 0; mi < 2; mi++)
#pragma unroll
      for (int kb = 0; kb < 4; kb++)
        af[mi][kb] = *(const h8*)(Pj + ((2 * w + mi) * 16 + n) * 128 + kb * 32 + q * 8);
#pragma unroll
    for (int nj = 0; nj < 8; nj++) {
      h8 bfr[4];
#pragma unroll
      for (int kb = 0; kb < 4; kb++)
        bfr[kb] = *(const h8*)&Dt[(nj * 16 + n) * 136 + kb * 32 + q * 8];
#pragma unroll
      for (int mi = 0; mi < 2; mi++) {
#pragma unroll
        for (int kb = 0; kb < 4; kb++)
          acc[mi][nj] = __builtin_amdgcn_mfma_f32_16x16x32_f16(af[mi][kb], bfr[kb], acc[mi][nj], 0, 0, 0);
        acc[mi][nj] = __builtin_amdgcn_mfma_f32_16x16x32_f16(
            af[mi][nj >> 1], (nj & 1) ? idO : idE, acc[mi][nj], 0, 0, 0);
      }
    }
    float dv0 = 0.f, dv1 = 0.f;
#pragma unroll
    for (int kb = 0; kb < 4; kb++) {
      float4 p0 = *(const float4*)&v32[kb * 32 + q * 8];
      float4 p1 = *(const float4*)&v32[kb * 32 + q * 8 + 4];
      float vk[8] = {p0.x, p0.y, p0.z, p0.w, p1.x, p1.y, p1.z, p1.w};
#pragma unroll
      for (int jj = 0; jj < 8; jj++) {
        dv0 += (float)af[0][kb][jj] * vk[jj];
        dv1 += (float)af[1][kb][jj] * vk[jj];
      }
    }
    dv0 += __shfl_xor(dv0, 16); dv0 += __shfl_xor(dv0, 32);
    dv1 += __shfl_xor(dv1, 16); dv1 += __shfl_xor(dv1, 32);
    float vold0 = v32[r0], vold1 = v32[r1];
    float vj0 = 0.f, vj1 = 0.f;
    if (q == 0) {
      vj0 = in_v[(nbase + j) * 128 + r0];
      vj1 = in_v[(nbase + j) * 128 + r1];
    }
    __syncthreads();
#pragma unroll
    for (int mi = 0; mi < 2; mi++) {
      int row0 = (2 * w + mi) * 16 + q * 4;
#pragma unroll
      for (int nj = 0; nj < 8; nj++) {
        int col = nj * 16 + n;
        union { _Float16 h[4]; uint2 u; } pk;
#pragma unroll
        for (int reg = 0; reg < 4; reg++) pk.h[reg] = (_Float16)acc[mi][nj][reg];
        *(uint2*)&Dt[col * 136 + row0] = pk.u;
      }
    }
    if (q == 0) {
      v32[r0] = vold0 + dv0 + vj0;
      v32[r1] = vold1 + dv1 + vj1;
    }
    __syncthreads();
  }
#pragma unroll
  for (int mi = 0; mi < 2; mi++) {
    int row0 = (2 * w + mi) * 16 + q * 4;
#pragma unroll
    for (int nj = 0; nj < 8; nj++) {
      int col = nj * 16 + n;
#pragma unroll
      for (int reg = 0; reg < 4; reg++)
        Dt[(row0 + reg) * 136 + col] = (_Float16)acc[mi][nj][reg];
    }
  }
  __syncthreads();
  _Float16* og = out_map + (size_t)blockIdx.x * 16384;
#pragma unroll
  for (int it = 0; it < 8; it++) {
    int idx = tid + it * 256;
    int rowl = idx >> 4, ch = idx & 15;
    uint4 val = *(const uint4*)&Dt[rowl * 136 + ch * 8];
    *(uint4*)(og + rowl * 128 + ch * 8) = val;
  }
  if (tid < 128) out_v[(size_t)blockIdx.x * 128 + tid] = v32[tid];
}

// ---------------- k_chainsuper: serial scan over supermaps ----------------
__global__ __launch_bounds__(256) void k_chainsuper(const _Float16* __restrict__ Sr,
                                                    const float* __restrict__ sv,
                                                    float* __restrict__ yb,
                                                    int c0, int scShift) {
  int b = blockIdx.x, tid = threadIdx.x;
  int NS = 1 << (scShift - 2);
  int i = tid >> 1, hh = tid & 1;
  __shared__ float ybuf[128];
  __shared__ float red[128];
  if (tid < 128) ybuf[tid] = yb[(size_t)(b * NC + c0) * 128 + tid];
  __syncthreads();

  uint4 arA[8], arB[8];
  float svA, svB;

#define LOADS(ar, svv, s)                                                            \
  {                                                                                  \
    const uint4* p = (const uint4*)(Sr + (size_t)(b * NS + (s)) * 16384 + i * 128 + hh * 64); \
    _Pragma("unroll")                                                                \
    for (int u = 0; u < 8; u++) ar[u] = p[u];                                        \
    svv = sv[(size_t)(b * NS + (s)) * 128 + i];                                      \
  }

#define STEPS(ar, svv, s)                                                            \
  {                                                                                  \
    float pt = 0.f;                                                                  \
    _Pragma("unroll")                                                                \
    for (int u = 0; u < 8; u++) {                                                    \
      union { uint4 v; _Float16 h[8]; } wv; wv.v = ar[u];                            \
      _Pragma("unroll")                                                              \
      for (int k = 0; k < 8; k++) pt += (float)wv.h[k] * ybuf[hh * 64 + u * 8 + k];  \
    }                                                                                \
    if (hh) red[i] = pt;                                                             \
    __syncthreads();                                                                 \
    if (!hh) {                                                                       \
      float yn = ybuf[i] + pt + red[i] + svv;                                        \
      int cg = c0 + 4 * ((s) + 1);                                                   \
      if (cg < NC) yb[(size_t)(b * NC + cg) * 128 + i] = yn;                         \
      ybuf[i] = yn;                                                                  \
    }                                                                                \
    __syncthreads();                                                                 \
  }

  LOADS(arA, svA, 0);
  int s = 0;
  for (; s + 1 < NS; s += 2) {
    LOADS(arB, svB, s + 1);
    STEPS(arA, svA, s);
    if (s + 2 < NS) LOADS(arA, svA, s + 2);
    STEPS(arB, svB, s + 1);
  }
  if (s < NS) STEPS(arA, svA, s);
#undef LOADS
#undef STEPS
}

// ---------------- k_fill: intra-supermap boundaries (3 parallel matvecs) --
__global__ __launch_bounds__(256) void k_fill(const _Float16* __restrict__ Mr,
                                              const float* __restrict__ vch,
                                              float* __restrict__ yb,
                                              int c0, int scShift) {
  int tid = threadIdx.x;
  int NS = 1 << (scShift - 2);
  int b = blockIdx.x >> (scShift - 2);
  int s = blockIdx.x & (NS - 1);
  int i = tid >> 1, hh = tid & 1;
  __shared__ float ybuf[128];
  __shared__ float red[128];
  if (tid < 128) ybuf[tid] = yb[(size_t)(b * NC + c0 + 4 * s) * 128 + tid];
  __syncthreads();
  size_t node0 = ((size_t)b << scShift) + 4 * s;

  uint4 arA[8], arB[8];
  float vvA, vvB;

#define LOADF(ar, vv, k)                                                             \
  {                                                                                  \
    const uint4* p = (const uint4*)(Mr + (node0 + (k)) * 16384 + i * 128 + hh * 64); \
    _Pragma("unroll")                                                                \
    for (int u = 0; u < 8; u++) ar[u] = p[u];                                        \
    vv = vch[(node0 + (k)) * 128 + i];                                               \
  }

#define STEPF(ar, vv, k)                                                             \
  {                                                                                  \
    float pt = 0.f;                                                                  \
    _Pragma("unroll")                                                                \
    for (int u = 0; u < 8; u++) {                                                    \
      union { uint4 v; _Float16 h[8]; } wv; wv.v = ar[u];                            \
      _Pragma("unroll")                                                              \
      for (int kk = 0; kk < 8; kk++) pt += (float)wv.h[kk] * ybuf[hh * 64 + u * 8 + kk]; \
    }                                                                                \
    if (hh) red[i] = pt;                                                             \
    __syncthreads();                                                                 \
    if (!hh) {                                                                       \
      float yn = ybuf[i] + pt + red[i] + vv;                                         \
      yb[(size_t)(b * NC + c0 + 4 * s + (k) + 1) * 128 + i] = yn;                    \
      ybuf[i] = yn;                                                                  \
    }                                                                                \
    __syncthreads();                                                                 \
  }

  LOADF(arA, vvA, 0);
  LOADF(arB, vvB, 1);
  STEPF(arA, vvA, 0);
  LOADF(arA, vvA, 2);
  STEPF(arB, vvB, 1);
  STEPF(arA, vvA, 2);
#undef LOADF
#undef STEPF
}

// ---------------- k_emit ----------------
__global__ __launch_bounds__(256) void k_emit(const _Float16* __restrict__ A_sl,
                                              const float* __restrict__ Bs,
                                              const float* __restrict__ yb,
                                              float* __restrict__ out,
                                              int c0, int scShift) {
  int tid = threadIdx.x;
  int SC = 1 << scShift;
  int b = blockIdx.x >> scShift;
  int cc = blockIdx.x & (SC - 1);
  int c = c0 + cc;
  int i = tid >> 1, hh = tid & 1;
  __shared__ float ybuf[128];
  __shared__ float red[128];
  if (tid < 128) ybuf[tid] = yb[(size_t)(b * NC + c) * 128 + tid];
  __syncthreads();
  int nst = min(L_, T_ - c * L_);
  size_t sidx0 = (size_t)blockIdx.x * L_;
  size_t btb = (size_t)b * T_ + c * L_;

  uint4 arA[8], arB[8];
  float bsA, bsB;

#define LOADR(ar, bsv, l)                                                            \
  {                                                                                  \
    const uint4* p = (const uint4*)(A_sl + (sidx0 + (l)) * 16384 + i * 128 + hh * 64); \
    _Pragma("unroll")                                                                \
    for (int u = 0; u < 8; u++) ar[u] = p[u];                                        \
    bsv = Bs[(btb + (l)) * 128 + i];                                                 \
  }

#define STEPE(ar, bsv, l)                                                            \
  {                                                                                  \
    float pt = 0.f;                                                                  \
    _Pragma("unroll")                                                                \
    for (int u = 0; u < 8; u++) {                                                    \
      union { uint4 v; _Float16 h[8]; } wv; wv.v = ar[u];                            \
      _Pragma("unroll")                                                              \
      for (int k = 0; k < 8; k++) pt += (float)wv.h[k] * ybuf[hh * 64 + u * 8 + k];  \
    }                                                                                \
    if (hh) red[i] = pt;                                                             \
    __syncthreads();                                                                 \
    if (!hh) {                                                                       \
      float yn = ybuf[i] + pt + red[i] + bsv;                                        \
      out[((size_t)b * S_ + (size_t)(c * L_ + (l) + 1)) * 128 + i] = yn;             \
      ybuf[i] = yn;                                                                  \
    }                                                                                \
    __syncthreads();                                                                 \
  }

  LOADR(arA, bsA, 0);
  for (int l = 0; l < nst; l += 2) {
    if (l + 1 < nst) LOADR(arB, bsB, l + 1);
    STEPE(arA, bsA, l);
    if (l + 2 < nst) LOADR(arA, bsA, l + 2);
    if (l + 1 < nst) STEPE(arB, bsB, l + 1);
  }
#undef LOADR
#undef STEPE
}

// ---------------- fallback: plain sequential ----------------
__global__ __launch_bounds__(256) void k_seq(const float* __restrict__ X,
                                             const float* __restrict__ Wa,
                                             const float* __restrict__ Wb,
                                             float* __restrict__ out) {
  int b = blockIdx.x, tid = threadIdx.x;
  int i = tid >> 1, hh = tid & 1;
  __shared__ float y[H_], red[H_], xs[D_], bts[H_];
  if (tid < H_) y[tid] = out[(size_t)b * S_ * H_ + tid];
  __syncthreads();
  for (int t = 1; t < S_; t++) {
    if (tid < D_) xs[tid] = X[((size_t)b * S_ + t) * D_ + tid] * DTC;
    __syncthreads();
    if (tid < H_) {
      const float* wr = Wb + tid * KD;
      float acc = wr[0] * DTC;
#pragma unroll 8
      for (int d = 0; d < D_; d++) acc += xs[d] * wr[1 + d];
      bts[tid] = acc;
    }
    float part = 0.f;
    const float* yhalf = &y[hh * 64];
    for (int j = 0; j < 64; j++) {
      const float* wr = Wa + ((size_t)(i * H_) + hh * 64 + j) * KD;
      float a = wr[0] * DTC;
#pragma unroll 8
      for (int d = 0; d < D_; d++) a += xs[d] * wr[1 + d];
      part += a * yhalf[j];
    }
    if (hh) red[i] = part;
    __syncthreads();
    if (!hh) {
      float yn = y[i] + part + red[i] + bts[i];
      out[((size_t)b * S_ + t) * H_ + i] = yn;
      y[i] = yn;
    }
    __syncthreads();
  }
}

extern "C" void kernel_launch(void* const* d_in, const int* in_sizes, int n_in,
                              void* d_out, int out_size, void* d_ws, size_t ws_size,
                              hipStream_t stream) {
  (void)in_sizes; (void)n_in; (void)out_size;
  const float* X  = (const float*)d_in[0];
  const float* Wi = (const float*)d_in[1];
  const float* bi = (const float*)d_in[2];
  const float* Wa = (const float*)d_in[3];
  const float* Wb = (const float*)d_in[4];
  float* out = (float*)d_out;
  char* ws = (char*)d_ws;

  size_t off = 0;
  auto alloc = [&](size_t bytes) { size_t o = off; off = (off + bytes + 255) & ~(size_t)255; return o; };
  size_t oBs  = alloc((size_t)B_ * T_ * 128 * 4);       //  8.38 MB
  size_t oYb  = alloc((size_t)B_ * NC * 128 * 4);       //  1.05 MB
  size_t oWaB = alloc((size_t)64 * 16384 * 2);          //  2.10 MB
  size_t oWa0 = alloc((size_t)16384 * 4);
  size_t oXs  = alloc((size_t)B_ * T_ * 64 * 2);        //  2.10 MB
  size_t fixed = off;

  const size_t APC  = (size_t)B_ * L_ * 16384 * 2;      // 2.10 MB
  const size_t MRPC = (size_t)B_ * 16384 * 2;           // 0.26 MB
  const size_t VCPC = (size_t)B_ * 128 * 4;             // 4 KB
  const size_t SRPC = (size_t)B_ * 16384 * 2 / 4;       // 64 KB
  const size_t SVPC = (size_t)B_ * 128;
  const size_t PER_SC = APC + MRPC + VCPC + SRPC + SVPC + 5 * 256;

  // R14: cap SC at 32 so the A slice (67 MB) + working set stays resident
  // in the 256 MB Infinity Cache across amat -> chunkmap -> ... -> emit.
  int SC = 0;
  if (ws_size > fixed) {
    size_t avail = ws_size - fixed;
    SC = 32;
    while (SC >= 4 && (size_t)SC * PER_SC > avail) SC >>= 1;
    if (SC < 4) SC = 0;
  }
  if (SC < 4) {
    k_y0<<<B_, 128, 0, stream>>>(X, Wi, bi, out, nullptr);
    k_seq<<<B_, 256, 0, stream>>>(X, Wa, Wb, out);
    return;
  }
  int scShift = __builtin_ctz(SC);

  size_t oMr = alloc((size_t)SC * MRPC);
  size_t oVc = alloc((size_t)SC * VCPC);
  size_t oSr = alloc((size_t)SC * SRPC);
  size_t oSv = alloc((size_t)SC * SVPC);
  size_t oA  = alloc((size_t)SC * APC);

  float*    Bs    = (float*)(ws + oBs);
  float*    yb    = (float*)(ws + oYb);
  _Float16* Wa16B = (_Float16*)(ws + oWaB);
  float*    Wa0   = (float*)(ws + oWa0);
  _Float16* Xs16  = (_Float16*)(ws + oXs);
  _Float16* Mr    = (_Float16*)(ws + oMr);
  float*    vch   = (float*)(ws + oVc);
  _Float16* Sr    = (_Float16*)(ws + oSr);
  float*    sv    = (float*)(ws + oSv);
  _Float16* A_sl  = (_Float16*)(ws + oA);

  k_prep_wa<<<4096, 256, 0, stream>>>(Wa, Wa16B, Wa0);
  k_prep_x<<<4094, 256, 0, stream>>>(X, Xs16);
  k_y0<<<B_, 128, 0, stream>>>(X, Wi, bi, out, yb);
  k_bs<<<(B_ * T_ + 15) / 16, 256, 0, stream>>>(X, Wb, Bs);

  int nslices = NC / SC;
  int chunks = B_ * SC;
  int amat_gx = (B_ * SC * L_) / 32;
  for (int si = 0; si < nslices; si++) {
    int c0 = si * SC;
    k_amat<<<dim3(amat_gx, 32), 256, 0, stream>>>(Xs16, Wa16B, Wa0, A_sl, c0, scShift);
    k_chunkmap<<<chunks, 256, 0, stream>>>(A_sl, Bs, Mr, vch, c0, scShift);
    k_comp4<<<chunks / 4, 256, 0, stream>>>(Mr, vch, Sr, sv);      // chunks -> supermaps
    k_chainsuper<<<B_, 256, 0, stream>>>(Sr, sv, yb, c0, scShift);
    k_fill<<<chunks / 4, 256, 0, stream>>>(Mr, vch, yb, c0, scShift);
    k_emit<<<chunks, 256, 0, stream>>>(A_sl, Bs, yb, out, c0, scShift);
  }
}

// Round 15
// 608.349 us; speedup vs baseline: 1.3098x; 1.3098x over previous
//
#include <hip/hip_runtime.h>
#include <hip/hip_fp16.h>

// LinearCDE chunked parallel scan, MFMA edition, adaptive workspace.
//   y_t = y_{t-1} + A_t y_{t-1} + b_t;  A_t = reshape(inp_t @ Wa^T, [H,H])
// R15: revert R14's SC=32 (regressed 616->797: halved grids + doubled
// per-slice fixed costs swamped any LLC gain). Back to SC=64, plus
// dispatch consolidation: (1) k_fill folded into k_emit — emit starts at
// the supermap boundary yb[4s] and applies k<=3 prefix matvecs with the
// same Mr maps in the same order fill used (bit-identical y); (2) prep
// kernels merged 4->2. 28 -> 22 dispatches, 6 -> 5 serial stages/slice.
// Pipeline: amat v2, chunkmap (7 fused serial compositions), comp4
// (chunks->supermaps), chainsuper, emit(+fill).

typedef _Float16 h8 __attribute__((ext_vector_type(8)));
typedef float v4f __attribute__((ext_vector_type(4)));
typedef unsigned int uint;

constexpr int B_ = 8, S_ = 2048, D_ = 64, H_ = 128;
constexpr int T_ = S_ - 1;              // 2047
constexpr int KD = D_ + 1;              // 65
constexpr float DTC = 1.0f / 2047.0f;
constexpr int L_ = 8;                   // chunk length
constexpr int LSH = 3;                  // log2(L_)
constexpr int NC = 256;                 // chunks per batch (last has 7 steps)

// ---------------- prep0: Wa16B swizzle + Wa0 + Xs16 ----------------
__global__ __launch_bounds__(256) void k_prep0(const float* __restrict__ Wa,
                                               _Float16* __restrict__ Wa16B,
                                               float* __restrict__ Wa0,
                                               const float* __restrict__ X,
                                               _Float16* __restrict__ Xs16) {
  int bx = blockIdx.x;
  if (bx < 4096) {
    int idx = bx * 256 + threadIdx.x;     // 16384*64 exact
    int r = idx >> 6, kk = idx & 63;
    int rt = r >> 4, n = r & 15;
    int kb = kk >> 5, q = (kk >> 3) & 3, jj = kk & 7;
    float v = Wa[(size_t)r * KD + 1 + kk];
    Wa16B[((((size_t)rt * 2 + kb) * 4 + q) * 16 + n) * 8 + jj] = (_Float16)v;
    if (kk == 0) Wa0[r] = Wa[(size_t)r * KD];
  } else {
    int idx = (bx - 4096) * 256 + threadIdx.x;   // 16376*64 exact
    if (idx < B_ * T_ * 64) {
      int bt = idx >> 6, d = idx & 63;
      int b = bt / T_, s = bt - b * T_;
      Xs16[(size_t)bt * 64 + d] = (_Float16)(X[((size_t)b * S_ + s + 1) * D_ + d] * DTC);
    }
  }
}

// ---------------- prep1: Bs (blocks 0..1023) + y0 (blocks 1024..1031) -----
__global__ __launch_bounds__(256) void k_prep1(const float* __restrict__ X,
                                               const float* __restrict__ Wb,
                                               float* __restrict__ Bs,
                                               const float* __restrict__ Wi,
                                               const float* __restrict__ bi,
                                               float* __restrict__ out,
                                               float* __restrict__ yb) {
  int tid = threadIdx.x;
  if (blockIdx.x >= 1024) {
    // y0 body
    int b = blockIdx.x - 1024;
    __shared__ float xs0[D_];
    if (tid < D_) xs0[tid] = X[(size_t)b * S_ * D_ + tid];
    __syncthreads();
    if (tid < H_) {
      float acc = bi[tid];
      const float* wr = Wi + tid * D_;
#pragma unroll 8
      for (int d = 0; d < D_; d++) acc += xs0[d] * wr[d];
      out[(size_t)b * S_ * H_ + tid] = acc;
      yb[(size_t)(b * NC + 0) * H_ + tid] = acc;
    }
    return;
  }
  __shared__ float wb_s[H_ * KD];
  __shared__ float xs[16][D_ + 4];
  int bt0 = blockIdx.x * 16;
  for (int i = tid; i < H_ * KD; i += 256) wb_s[i] = Wb[i];
  for (int i = tid; i < 16 * D_; i += 256) {
    int sl = i >> 6, d = i & 63;
    int btg = bt0 + sl;
    float v = 0.f;
    if (btg < B_ * T_) {
      int b = btg / T_, s = btg - b * T_;
      v = X[((size_t)b * S_ + s + 1) * D_ + d] * DTC;
    }
    xs[sl][d] = v;
  }
  __syncthreads();
  int h = tid & 127, sh = tid >> 7;
  const float* wrow = &wb_s[h * KD];
  for (int u = 0; u < 8; u++) {
    int sl = sh * 8 + u;
    int btg = bt0 + sl;
    if (btg >= B_ * T_) break;
    float acc = wrow[0] * DTC;
#pragma unroll 8
    for (int d = 0; d < D_; d++) acc += xs[sl][d] * wrow[1 + d];
    Bs[(size_t)btg * H_ + h] = acc;
  }
}

// ---------------- k_amat v2: 32t x 512el tiles, contiguous 1KB writes -----
__global__ __launch_bounds__(256) void k_amat(const _Float16* __restrict__ Xs16,
                                              const _Float16* __restrict__ Wa16B,
                                              const float* __restrict__ Wa0,
                                              _Float16* __restrict__ A_sl,
                                              int c0, int scShift) {
  __shared__ _Float16 sb[32 * 528];    // 33.8 KB
  int tid = threadIdx.x;
  int w = tid >> 6, lane = tid & 63;
  int n = lane & 15, q = lane >> 4;
  int rowbase = blockIdx.x * 32;
  int SCm = ((1 << scShift) << LSH) - 1;

  h8 af[2][2];
#pragma unroll
  for (int mi = 0; mi < 2; mi++) {
    int sidx = rowbase + mi * 16 + n;
    int b = sidx >> (scShift + LSH);
    int rem = sidx & SCm;
    int cc = rem >> LSH, l = rem & (L_ - 1);
    int s = (c0 + cc) * L_ + l;
    if (s >= T_) s = T_ - 1;
    size_t btg = (size_t)b * T_ + s;
#pragma unroll
    for (int kb = 0; kb < 2; kb++)
      af[mi][kb] = *(const h8*)(Xs16 + btg * 64 + kb * 32 + q * 8);
  }

  v4f acc[2][8];
#pragma unroll
  for (int nj = 0; nj < 8; nj++) {
    int ct_g = blockIdx.y * 32 + w * 8 + nj;
    float binit = DTC * Wa0[ct_g * 16 + n];
    h8 bf0 = *(const h8*)(Wa16B + ((((size_t)ct_g * 2 + 0) * 4 + q) * 16 + n) * 8);
    h8 bf1 = *(const h8*)(Wa16B + ((((size_t)ct_g * 2 + 1) * 4 + q) * 16 + n) * 8);
#pragma unroll
    for (int mi = 0; mi < 2; mi++) {
      v4f a;
      a[0] = binit; a[1] = binit; a[2] = binit; a[3] = binit;
      a = __builtin_amdgcn_mfma_f32_16x16x32_f16(af[mi][0], bf0, a, 0, 0, 0);
      a = __builtin_amdgcn_mfma_f32_16x16x32_f16(af[mi][1], bf1, a, 0, 0, 0);
      acc[mi][nj] = a;
    }
  }
#pragma unroll
  for (int mi = 0; mi < 2; mi++)
#pragma unroll
    for (int nj = 0; nj < 8; nj++)
#pragma unroll
      for (int reg = 0; reg < 4; reg++)
        sb[(mi * 16 + q * 4 + reg) * 528 + w * 128 + ((nj * 16 + n) ^ (q * 16))] =
            (_Float16)acc[mi][nj][reg];
  __syncthreads();
#pragma unroll
  for (int it = 0; it < 8; it++) {
    int idx = tid + it * 256;
    int t = idx >> 6, u4 = idx & 63;
    int qt = (t >> 2) & 3;
    uint4 val = *(const uint4*)&sb[t * 528 + ((u4 * 8) ^ (qt * 16))];
    *(uint4*)(A_sl + (size_t)(rowbase + t) * 16384 + blockIdx.y * 512 + u4 * 8) = val;
  }
}

// ---------------- k_chunkmap: chunk map via 7 serial compositions --------
__global__ __launch_bounds__(256) void k_chunkmap(const _Float16* __restrict__ A_sl,
                                                  const float* __restrict__ Bs,
                                                  _Float16* __restrict__ Mr,
                                                  float* __restrict__ vch,
                                                  int c0, int scShift) {
  __shared__ _Float16 Dt[128 * 136];
  __shared__ float v32[128];
  int tid = threadIdx.x;
  int w = tid >> 6, lane = tid & 63;
  int n = lane & 15, q = lane >> 4;
  int chunk = blockIdx.x;
  int SC = 1 << scShift;
  int b = chunk >> scShift;
  int cc = chunk & (SC - 1);
  int c = c0 + cc;
  int sbase = c * L_;
  int nsteps = min(L_, T_ - sbase);
  const _Float16* Abase = A_sl + (size_t)chunk * L_ * 16384;
  size_t btb = (size_t)b * T_ + sbase;

  // stage A0^T (conflict-free R10 mapping)
#pragma unroll
  for (int it = 0; it < 8; it++) {
    int idx = tid + it * 256;
    int rowl = idx & 127, c8 = (idx >> 7) * 8;
    uint4 pk = *(const uint4*)(Abase + rowl * 128 + c8);
    const _Float16* hp = (const _Float16*)&pk;
#pragma unroll
    for (int cx = 0; cx < 8; cx++) Dt[(c8 + cx) * 136 + rowl] = hp[cx];
  }
  if (tid < 128) v32[tid] = Bs[btb * 128 + tid];
  h8 idE, idO;
#pragma unroll
  for (int jj = 0; jj < 8; jj++) {
    idE[jj] = (_Float16)((q * 8 + jj == n) ? 1.f : 0.f);
    idO[jj] = (_Float16)((q * 8 + jj == 16 + n) ? 1.f : 0.f);
  }
  __syncthreads();

  v4f acc[2][8];
#pragma unroll
  for (int mi = 0; mi < 2; mi++) {
    int row0 = (2 * w + mi) * 16 + q * 4;
#pragma unroll
    for (int nj = 0; nj < 8; nj++) {
      int col = nj * 16 + n;
      union { uint2 u; _Float16 h[4]; } m2;
      m2.u = *(const uint2*)&Dt[col * 136 + row0];
#pragma unroll
      for (int reg = 0; reg < 4; reg++) acc[mi][nj][reg] = (float)m2.h[reg];
    }
  }

  int r0 = 2 * w * 16 + n, r1 = r0 + 16;
  h8 afA[2][4], afB[2][4];   // named double buffers, constant indices only

#define LOADA(dst, l)                                                                \
  {                                                                                  \
    const _Float16* Ag = Abase + (size_t)(l) * 16384;                                \
    _Pragma("unroll")                                                                \
    for (int mi = 0; mi < 2; mi++)                                                   \
      _Pragma("unroll")                                                              \
      for (int kb = 0; kb < 4; kb++)                                                 \
        dst[mi][kb] = *(const h8*)(Ag + ((2 * w + mi) * 16 + n) * 128 + kb * 32 + q * 8); \
  }

#define STEPQ(af, l)                                                                 \
  {                                                                                  \
    _Pragma("unroll")                                                                \
    for (int nj = 0; nj < 8; nj++) {                                                 \
      h8 bfr[4];                                                                     \
      _Pragma("unroll")                                                              \
      for (int kb = 0; kb < 4; kb++)                                                 \
        bfr[kb] = *(const h8*)&Dt[(nj * 16 + n) * 136 + kb * 32 + q * 8];            \
      _Pragma("unroll")                                                              \
      for (int mi = 0; mi < 2; mi++) {                                               \
        _Pragma("unroll")                                                            \
        for (int kb = 0; kb < 4; kb++)                                               \
          acc[mi][nj] = __builtin_amdgcn_mfma_f32_16x16x32_f16(af[mi][kb], bfr[kb], acc[mi][nj], 0, 0, 0); \
        acc[mi][nj] = __builtin_amdgcn_mfma_f32_16x16x32_f16(                        \
            af[mi][nj >> 1], (nj & 1) ? idO : idE, acc[mi][nj], 0, 0, 0);            \
      }                                                                              \
    }                                                                                \
    float dv0 = 0.f, dv1 = 0.f;                                                      \
    _Pragma("unroll")                                                                \
    for (int kb = 0; kb < 4; kb++) {                                                 \
      float4 p0 = *(const float4*)&v32[kb * 32 + q * 8];                             \
      float4 p1 = *(const float4*)&v32[kb * 32 + q * 8 + 4];                         \
      float vk[8] = {p0.x, p0.y, p0.z, p0.w, p1.x, p1.y, p1.z, p1.w};                \
      _Pragma("unroll")                                                              \
      for (int jj = 0; jj < 8; jj++) {                                               \
        dv0 += (float)af[0][kb][jj] * vk[jj];                                        \
        dv1 += (float)af[1][kb][jj] * vk[jj];                                        \
      }                                                                              \
    }                                                                                \
    dv0 += __shfl_xor(dv0, 16); dv0 += __shfl_xor(dv0, 32);                          \
    dv1 += __shfl_xor(dv1, 16); dv1 += __shfl_xor(dv1, 32);                          \
    float vold0 = v32[r0], vold1 = v32[r1];                                          \
    float bs0 = 0.f, bs1 = 0.f;                                                      \
    if (q == 0) {                                                                    \
      bs0 = Bs[(btb + (l)) * 128 + r0];                                              \
      bs1 = Bs[(btb + (l)) * 128 + r1];                                              \
    }                                                                                \
    __syncthreads();                                                                 \
    _Pragma("unroll")                                                                \
    for (int mi = 0; mi < 2; mi++) {                                                 \
      int row0 = (2 * w + mi) * 16 + q * 4;                                          \
      _Pragma("unroll")                                                              \
      for (int nj = 0; nj < 8; nj++) {                                               \
        int col = nj * 16 + n;                                                       \
        union { _Float16 h[4]; uint2 u; } pk;                                        \
        _Pragma("unroll")                                                            \
        for (int reg = 0; reg < 4; reg++) pk.h[reg] = (_Float16)acc[mi][nj][reg];    \
        *(uint2*)&Dt[col * 136 + row0] = pk.u;                                       \
      }                                                                              \
    }                                                                                \
    if (q == 0) {                                                                    \
      v32[r0] = vold0 + dv0 + bs0;                                                   \
      v32[r1] = vold1 + dv1 + bs1;                                                   \
    }                                                                                \
    __syncthreads();                                                                 \
  }

  LOADA(afA, 1);
  for (int l = 1; l < nsteps; l += 2) {
    if (l + 1 < nsteps) LOADA(afB, l + 1);
    STEPQ(afA, l);
    if (l + 2 < nsteps) LOADA(afA, l + 2);
    if (l + 1 < nsteps) STEPQ(afB, l + 1);
  }
#undef LOADA
#undef STEPQ

#pragma unroll
  for (int mi = 0; mi < 2; mi++) {
    int row0 = (2 * w + mi) * 16 + q * 4;
#pragma unroll
    for (int nj = 0; nj < 8; nj++) {
      int col = nj * 16 + n;
#pragma unroll
      for (int reg = 0; reg < 4; reg++)
        Dt[(row0 + reg) * 136 + col] = (_Float16)acc[mi][nj][reg];
    }
  }
  __syncthreads();
  _Float16* og = Mr + (size_t)chunk * 16384;
#pragma unroll
  for (int it = 0; it < 8; it++) {
    int idx = tid + it * 256;
    int rowl = idx >> 4, ch = idx & 15;
    uint4 val = *(const uint4*)&Dt[rowl * 136 + ch * 8];
    *(uint4*)(og + rowl * 128 + ch * 8) = val;
  }
  if (tid < 128) vch[(size_t)chunk * 128 + tid] = v32[tid];
}

// ---------------- k_comp4: compose 4 consecutive delta maps --------------
__global__ __launch_bounds__(256) void k_comp4(const _Float16* __restrict__ in_map,
                                               const float* __restrict__ in_v,
                                               _Float16* __restrict__ out_map,
                                               float* __restrict__ out_v) {
  __shared__ _Float16 Dt[128 * 136];    // D transposed
  __shared__ float v32[128];
  int tid = threadIdx.x;
  int w = tid >> 6, lane = tid & 63;
  int n = lane & 15, q = lane >> 4;
  size_t nbase = (size_t)blockIdx.x * 4;

  const _Float16* P0 = in_map + nbase * 16384;
#pragma unroll
  for (int it = 0; it < 8; it++) {
    int idx = tid + it * 256;
    int rowl = idx & 127, c8 = (idx >> 7) * 8;
    uint4 pk = *(const uint4*)(P0 + rowl * 128 + c8);
    const _Float16* hp = (const _Float16*)&pk;
#pragma unroll
    for (int cx = 0; cx < 8; cx++) Dt[(c8 + cx) * 136 + rowl] = hp[cx];
  }
  if (tid < 128) v32[tid] = in_v[nbase * 128 + tid];
  h8 idE, idO;
#pragma unroll
  for (int jj = 0; jj < 8; jj++) {
    idE[jj] = (_Float16)((q * 8 + jj == n) ? 1.f : 0.f);
    idO[jj] = (_Float16)((q * 8 + jj == 16 + n) ? 1.f : 0.f);
  }
  __syncthreads();

  v4f acc[2][8];
#pragma unroll
  for (int mi = 0; mi < 2; mi++) {
    int row0 = (2 * w + mi) * 16 + q * 4;
#pragma unroll
    for (int nj = 0; nj < 8; nj++) {
      int col = nj * 16 + n;
      union { uint2 u; _Float16 h[4]; } m2;
      m2.u = *(const uint2*)&Dt[col * 136 + row0];
#pragma unroll
      for (int reg = 0; reg < 4; reg++) acc[mi][nj][reg] = (float)m2.h[reg];
    }
  }

  int r0 = 2 * w * 16 + n, r1 = r0 + 16;
  for (int j = 1; j < 4; j++) {
    const _Float16* Pj = in_map + (nbase + j) * 16384;
    h8 af[2][4];
#pragma unroll
    for (int mi = 0; mi < 2; mi++)
#pragma unroll
      for (int kb = 0; kb < 4; kb++)
        af[mi][kb] = *(const h8*)(Pj + ((2 * w + mi) * 16 + n) * 128 + kb * 32 + q * 8);
#pragma unroll
    for (int nj = 0; nj < 8; nj++) {
      h8 bfr[4];
#pragma unroll
      for (int kb = 0; kb < 4; kb++)
        bfr[kb] = *(const h8*)&Dt[(nj * 16 + n) * 136 + kb * 32 + q * 8];
#pragma unroll
      for (int mi = 0; mi < 2; mi++) {
#pragma unroll
        for (int kb = 0; kb < 4; kb++)
          acc[mi][nj] = __builtin_amdgcn_mfma_f32_16x16x32_f16(af[mi][kb], bfr[kb], acc[mi][nj], 0, 0, 0);
        acc[mi][nj] = __builtin_amdgcn_mfma_f32_16x16x32_f16(
            af[mi][nj >> 1], (nj & 1) ? idO : idE, acc[mi][nj], 0, 0, 0);
      }
    }
    float dv0 = 0.f, dv1 = 0.f;
#pragma unroll
    for (int kb = 0; kb < 4; kb++) {
      float4 p0 = *(const float4*)&v32[kb * 32 + q * 8];
      float4 p1 = *(const float4*)&v32[kb * 32 + q * 8 + 4];
      float vk[8] = {p0.x, p0.y, p0.z, p0.w, p1.x, p1.y, p1.z, p1.w};
#pragma unroll
      for (int jj = 0; jj < 8; jj++) {
        dv0 += (float)af[0][kb][jj] * vk[jj];
        dv1 += (float)af[1][kb][jj] * vk[jj];
      }
    }
    dv0 += __shfl_xor(dv0, 16); dv0 += __shfl_xor(dv0, 32);
    dv1 += __shfl_xor(dv1, 16); dv1 += __shfl_xor(dv1, 32);
    float vold0 = v32[r0], vold1 = v32[r1];
    float vj0 = 0.f, vj1 = 0.f;
    if (q == 0) {
      vj0 = in_v[(nbase + j) * 128 + r0];
      vj1 = in_v[(nbase + j) * 128 + r1];
    }
    __syncthreads();
#pragma unroll
    for (int mi = 0; mi < 2; mi++) {
      int row0 = (2 * w + mi) * 16 + q * 4;
#pragma unroll
      for (int nj = 0; nj < 8; nj++) {
        int col = nj * 16 + n;
        union { _Float16 h[4]; uint2 u; } pk;
#pragma unroll
        for (int reg = 0; reg < 4; reg++) pk.h[reg] = (_Float16)acc[mi][nj][reg];
        *(uint2*)&Dt[col * 136 + row0] = pk.u;
      }
    }
    if (q == 0) {
      v32[r0] = vold0 + dv0 + vj0;
      v32[r1] = vold1 + dv1 + vj1;
    }
    __syncthreads();
  }
#pragma unroll
  for (int mi = 0; mi < 2; mi++) {
    int row0 = (2 * w + mi) * 16 + q * 4;
#pragma unroll
    for (int nj = 0; nj < 8; nj++) {
      int col = nj * 16 + n;
#pragma unroll
      for (int reg = 0; reg < 4; reg++)
        Dt[(row0 + reg) * 136 + col] = (_Float16)acc[mi][nj][reg];
    }
  }
  __syncthreads();
  _Float16* og = out_map + (size_t)blockIdx.x * 16384;
#pragma unroll
  for (int it = 0; it < 8; it++) {
    int idx = tid + it * 256;
    int rowl = idx >> 4, ch = idx & 15;
    uint4 val = *(const uint4*)&Dt[rowl * 136 + ch * 8];
    *(uint4*)(og + rowl * 128 + ch * 8) = val;
  }
  if (tid < 128) out_v[(size_t)blockIdx.x * 128 + tid] = v32[tid];
}

// ---------------- k_chainsuper: serial scan over supermaps ----------------
__global__ __launch_bounds__(256) void k_chainsuper(const _Float16* __restrict__ Sr,
                                                    const float* __restrict__ sv,
                                                    float* __restrict__ yb,
                                                    int c0, int scShift) {
  int b = blockIdx.x, tid = threadIdx.x;
  int NS = 1 << (scShift - 2);
  int i = tid >> 1, hh = tid & 1;
  __shared__ float ybuf[128];
  __shared__ float red[128];
  if (tid < 128) ybuf[tid] = yb[(size_t)(b * NC + c0) * 128 + tid];
  __syncthreads();

  uint4 arA[8], arB[8];
  float svA, svB;

#define LOADS(ar, svv, s)                                                            \
  {                                                                                  \
    const uint4* p = (const uint4*)(Sr + (size_t)(b * NS + (s)) * 16384 + i * 128 + hh * 64); \
    _Pragma("unroll")                                                                \
    for (int u = 0; u < 8; u++) ar[u] = p[u];                                        \
    svv = sv[(size_t)(b * NS + (s)) * 128 + i];                                      \
  }

#define STEPS(ar, svv, s)                                                            \
  {                                                                                  \
    float pt = 0.f;                                                                  \
    _Pragma("unroll")                                                                \
    for (int u = 0; u < 8; u++) {                                                    \
      union { uint4 v; _Float16 h[8]; } wv; wv.v = ar[u];                            \
      _Pragma("unroll")                                                              \
      for (int k = 0; k < 8; k++) pt += (float)wv.h[k] * ybuf[hh * 64 + u * 8 + k];  \
    }                                                                                \
    if (hh) red[i] = pt;                                                             \
    __syncthreads();                                                                 \
    if (!hh) {                                                                       \
      float yn = ybuf[i] + pt + red[i] + svv;                                        \
      int cg = c0 + 4 * ((s) + 1);                                                   \
      if (cg < NC) yb[(size_t)(b * NC + cg) * 128 + i] = yn;                         \
      ybuf[i] = yn;                                                                  \
    }                                                                                \
    __syncthreads();                                                                 \
  }

  LOADS(arA, svA, 0);
  int s = 0;
  for (; s + 1 < NS; s += 2) {
    LOADS(arB, svB, s + 1);
    STEPS(arA, svA, s);
    if (s + 2 < NS) LOADS(arA, svA, s + 2);
    STEPS(arB, svB, s + 1);
  }
  if (s < NS) STEPS(arA, svA, s);
#undef LOADS
#undef STEPS
}

// ---------------- k_emit (R15: fill folded in as prefix matvecs) ----------
__global__ __launch_bounds__(256) void k_emit(const _Float16* __restrict__ A_sl,
                                              const float* __restrict__ Bs,
                                              const _Float16* __restrict__ Mr,
                                              const float* __restrict__ vch,
                                              const float* __restrict__ yb,
                                              float* __restrict__ out,
                                              int c0, int scShift) {
  int tid = threadIdx.x;
  int SC = 1 << scShift;
  int b = blockIdx.x >> scShift;
  int cc = blockIdx.x & (SC - 1);
  int c = c0 + cc;
  int i = tid >> 1, hh = tid & 1;
  __shared__ float ybuf[128];
  __shared__ float red[128];
  int kpre = cc & 3;                 // prefix steps within supermap
  int cbase = c - kpre;              // supermap-aligned chunk
  if (tid < 128) ybuf[tid] = yb[(size_t)(b * NC + cbase) * 128 + tid];
  __syncthreads();
  size_t node0 = ((size_t)b << scShift) + (cc & ~3);

  uint4 arA[8], arB[8];
  float bsA, bsB;

  // prefix: apply kpre chunk maps (same sequence k_fill used -> bit-identical)
  for (int j = 0; j < kpre; j++) {
    const uint4* p = (const uint4*)(Mr + (node0 + j) * 16384 + i * 128 + hh * 64);
#pragma unroll
    for (int u = 0; u < 8; u++) arA[u] = p[u];
    float vv = vch[(node0 + j) * 128 + i];
    float pt = 0.f;
#pragma unroll
    for (int u = 0; u < 8; u++) {
      union { uint4 v; _Float16 h[8]; } wv; wv.v = arA[u];
#pragma unroll
      for (int k = 0; k < 8; k++) pt += (float)wv.h[k] * ybuf[hh * 64 + u * 8 + k];
    }
    if (hh) red[i] = pt;
    __syncthreads();
    if (!hh) {
      float yn = ybuf[i] + pt + red[i] + vv;
      ybuf[i] = yn;
    }
    __syncthreads();
  }

  int nst = min(L_, T_ - c * L_);
  size_t sidx0 = (size_t)blockIdx.x * L_;
  size_t btb = (size_t)b * T_ + c * L_;

#define LOADR(ar, bsv, l)                                                            \
  {                                                                                  \
    const uint4* p = (const uint4*)(A_sl + (sidx0 + (l)) * 16384 + i * 128 + hh * 64); \
    _Pragma("unroll")                                                                \
    for (int u = 0; u < 8; u++) ar[u] = p[u];                                        \
    bsv = Bs[(btb + (l)) * 128 + i];                                                 \
  }

#define STEPE(ar, bsv, l)                                                            \
  {                                                                                  \
    float pt = 0.f;                                                                  \
    _Pragma("unroll")                                                                \
    for (int u = 0; u < 8; u++) {                                                    \
      union { uint4 v; _Float16 h[8]; } wv; wv.v = ar[u];                            \
      _Pragma("unroll")                                                              \
      for (int k = 0; k < 8; k++) pt += (float)wv.h[k] * ybuf[hh * 64 + u * 8 + k];  \
    }                                                                                \
    if (hh) red[i] = pt;                                                             \
    __syncthreads();                                                                 \
    if (!hh) {                                                                       \
      float yn = ybuf[i] + pt + red[i] + bsv;                                        \
      out[((size_t)b * S_ + (size_t)(c * L_ + (l) + 1)) * 128 + i] = yn;             \
      ybuf[i] = yn;                                                                  \
    }                                                                                \
    __syncthreads();                                                                 \
  }

  LOADR(arA, bsA, 0);
  for (int l = 0; l < nst; l += 2) {
    if (l + 1 < nst) LOADR(arB, bsB, l + 1);
    STEPE(arA, bsA, l);
    if (l + 2 < nst) LOADR(arA, bsA, l + 2);
    if (l + 1 < nst) STEPE(arB, bsB, l + 1);
  }
#undef LOADR
#undef STEPE
}

// ---------------- fallback: plain sequential ----------------
__global__ __launch_bounds__(256) void k_seq(const float* __restrict__ X,
                                             const float* __restrict__ Wa,
                                             const float* __restrict__ Wb,
                                             float* __restrict__ out) {
  int b = blockIdx.x, tid = threadIdx.x;
  int i = tid >> 1, hh = tid & 1;
  __shared__ float y[H_], red[H_], xs[D_], bts[H_];
  if (tid < H_) y[tid] = out[(size_t)b * S_ * H_ + tid];
  __syncthreads();
  for (int t = 1; t < S_; t++) {
    if (tid < D_) xs[tid] = X[((size_t)b * S_ + t) * D_ + tid] * DTC;
    __syncthreads();
    if (tid < H_) {
      const float* wr = Wb + tid * KD;
      float acc = wr[0] * DTC;
#pragma unroll 8
      for (int d = 0; d < D_; d++) acc += xs[d] * wr[1 + d];
      bts[tid] = acc;
    }
    float part = 0.f;
    const float* yhalf = &y[hh * 64];
    for (int j = 0; j < 64; j++) {
      const float* wr = Wa + ((size_t)(i * H_) + hh * 64 + j) * KD;
      float a = wr[0] * DTC;
#pragma unroll 8
      for (int d = 0; d < D_; d++) a += xs[d] * wr[1 + d];
      part += a * yhalf[j];
    }
    if (hh) red[i] = part;
    __syncthreads();
    if (!hh) {
      float yn = y[i] + part + red[i] + bts[i];
      out[((size_t)b * S_ + t) * H_ + i] = yn;
      y[i] = yn;
    }
    __syncthreads();
  }
}

__global__ __launch_bounds__(128) void k_y0f(const float* __restrict__ X,
                                             const float* __restrict__ Wi,
                                             const float* __restrict__ bi,
                                             float* __restrict__ out) {
  int b = blockIdx.x, h = threadIdx.x;
  __shared__ float xs[D_];
  if (h < D_) xs[h] = X[(size_t)b * S_ * D_ + h];
  __syncthreads();
  float acc = bi[h];
  const float* wr = Wi + h * D_;
#pragma unroll 8
  for (int d = 0; d < D_; d++) acc += xs[d] * wr[d];
  out[(size_t)b * S_ * H_ + h] = acc;
}

extern "C" void kernel_launch(void* const* d_in, const int* in_sizes, int n_in,
                              void* d_out, int out_size, void* d_ws, size_t ws_size,
                              hipStream_t stream) {
  (void)in_sizes; (void)n_in; (void)out_size;
  const float* X  = (const float*)d_in[0];
  const float* Wi = (const float*)d_in[1];
  const float* bi = (const float*)d_in[2];
  const float* Wa = (const float*)d_in[3];
  const float* Wb = (const float*)d_in[4];
  float* out = (float*)d_out;
  char* ws = (char*)d_ws;

  size_t off = 0;
  auto alloc = [&](size_t bytes) { size_t o = off; off = (off + bytes + 255) & ~(size_t)255; return o; };
  size_t oBs  = alloc((size_t)B_ * T_ * 128 * 4);       //  8.38 MB
  size_t oYb  = alloc((size_t)B_ * NC * 128 * 4);       //  1.05 MB
  size_t oWaB = alloc((size_t)64 * 16384 * 2);          //  2.10 MB
  size_t oWa0 = alloc((size_t)16384 * 4);
  size_t oXs  = alloc((size_t)B_ * T_ * 64 * 2);        //  2.10 MB
  size_t fixed = off;

  const size_t APC  = (size_t)B_ * L_ * 16384 * 2;      // 2.10 MB
  const size_t MRPC = (size_t)B_ * 16384 * 2;           // 0.26 MB
  const size_t VCPC = (size_t)B_ * 128 * 4;             // 4 KB
  const size_t SRPC = (size_t)B_ * 16384 * 2 / 4;       // 64 KB
  const size_t SVPC = (size_t)B_ * 128;
  const size_t PER_SC = APC + MRPC + VCPC + SRPC + SVPC + 5 * 256;

  int SC = 0;
  if (ws_size > fixed) {
    size_t avail = ws_size - fixed;
    SC = 64;
    while (SC >= 4 && (size_t)SC * PER_SC > avail) SC >>= 1;
    if (SC < 4) SC = 0;
  }
  if (SC < 4) {
    k_y0f<<<B_, 128, 0, stream>>>(X, Wi, bi, out);
    k_seq<<<B_, 256, 0, stream>>>(X, Wa, Wb, out);
    return;
  }
  int scShift = __builtin_ctz(SC);

  size_t oMr = alloc((size_t)SC * MRPC);
  size_t oVc = alloc((size_t)SC * VCPC);
  size_t oSr = alloc((size_t)SC * SRPC);
  size_t oSv = alloc((size_t)SC * SVPC);
  size_t oA  = alloc((size_t)SC * APC);

  float*    Bs    = (float*)(ws + oBs);
  float*    yb    = (float*)(ws + oYb);
  _Float16* Wa16B = (_Float16*)(ws + oWaB);
  float*    Wa0   = (float*)(ws + oWa0);
  _Float16* Xs16  = (_Float16*)(ws + oXs);
  _Float16* Mr    = (_Float16*)(ws + oMr);
  float*    vch   = (float*)(ws + oVc);
  _Float16* Sr    = (_Float16*)(ws + oSr);
  float*    sv    = (float*)(ws + oSv);
  _Float16* A_sl  = (_Float16*)(ws + oA);

  k_prep0<<<4096 + 4094, 256, 0, stream>>>(Wa, Wa16B, Wa0, X, Xs16);
  k_prep1<<<1024 + B_, 256, 0, stream>>>(X, Wb, Bs, Wi, bi, out, yb);

  int nslices = NC / SC;
  int chunks = B_ * SC;
  int amat_gx = (B_ * SC * L_) / 32;
  for (int si = 0; si < nslices; si++) {
    int c0 = si * SC;
    k_amat<<<dim3(amat_gx, 32), 256, 0, stream>>>(Xs16, Wa16B, Wa0, A_sl, c0, scShift);
    k_chunkmap<<<chunks, 256, 0, stream>>>(A_sl, Bs, Mr, vch, c0, scShift);
    k_comp4<<<chunks / 4, 256, 0, stream>>>(Mr, vch, Sr, sv);      // chunks -> supermaps
    k_chainsuper<<<B_, 256, 0, stream>>>(Sr, sv, yb, c0, scShift);
    k_emit<<<chunks, 256, 0, stream>>>(A_sl, Bs, Mr, vch, yb, out, c0, scShift);
  }
}